// Round 5
// baseline (475.405 us; speedup 1.0000x reference)
//
#include <hip/hip_runtime.h>
#include <math.h>

// ---- problem constants ----
constexpr int B  = 32;
constexpr int N  = 196;
constexpr int D  = 768;
constexpr int E  = 200;
constexpr int TK = 20;

constexpr int NGRP = 4;        // expert groups (5 experts each)
constexpr int CH8  = 7168;     // fp8 chunk bytes: 224 rows x 32 k
constexpr int PRB  = 14336;    // 2-chunk period bytes
constexpr int EXB8 = 100352;   // per expert: W1 c0..6 | W2 c0..6
constexpr int LK   = 40;       // k_outproj LDS stride

typedef __bf16 bf16x8 __attribute__((ext_vector_type(8)));
typedef __bf16 bf16x4 __attribute__((ext_vector_type(4)));
typedef float  f32x4  __attribute__((ext_vector_type(4)));
typedef unsigned char uchar;

#define GLDS16(gp, lp)                                                        \
  __builtin_amdgcn_global_load_lds(                                           \
      (const __attribute__((address_space(1))) void*)(gp),                    \
      (__attribute__((address_space(3))) void*)(lp), 16, 0, 0)

#define WAITVM6   __builtin_amdgcn_s_waitcnt(0x0F76)  // vmcnt<=6
#define WAITVM0   __builtin_amdgcn_s_waitcnt(0x0F70)  // vmcnt==0
#define WAITLGKM0 __builtin_amdgcn_s_waitcnt(0xC07F)  // lgkmcnt==0
#define BAR       __builtin_amdgcn_s_barrier()

__device__ __forceinline__ float gelu_fast(float x) {
  float u = x * fmaf(x * x, 0.044715f, 1.0f);
  float e = exp2f(-2.3022084f * u);
  return x * __builtin_amdgcn_rcpf(1.0f + e);
}

__device__ __forceinline__ uchar f32_to_f8(float v) {
  return (uchar)(__builtin_amdgcn_cvt_pk_fp8_f32(v, v, 0, false) & 0xff);
}

// ---------------------------------------------------------------------------
// Kernel 1: token-mean + LN over N -> z fp8 (B,D,224) zero-padded rows.
// ---------------------------------------------------------------------------
__global__ __launch_bounds__(256) void k_ln(const float* __restrict__ x,
                                            uchar* __restrict__ zb,
                                            float* __restrict__ mu) {
  int b = blockIdx.x / 12, dt = blockIdx.x % 12;
  int d0 = dt * 64;
  int t = threadIdx.x;
  int q = t >> 6, d = t & 63;
  __shared__ float ps[256], pq[256];
  __shared__ float ms[64], rss[64];
  __shared__ alignas(16) uchar zt[64 * 224];

  const float* xp = x + ((size_t)b * N + q * 49) * D + d0 + d;
  float s = 0.f, sq = 0.f;
  #pragma unroll 7
  for (int n = 0; n < 49; ++n) {
    float v = xp[(size_t)n * D];
    s += v; sq += v * v;
  }
  ps[t] = s; pq[t] = sq;
  __syncthreads();
  if (t < 64) {
    float S = ps[t] + ps[t + 64] + ps[t + 128] + ps[t + 192];
    float Q = pq[t] + pq[t + 64] + pq[t + 128] + pq[t + 192];
    float m = S * (1.0f / N);
    float var = Q * (1.0f / N) - m * m;
    ms[t] = m; rss[t] = rsqrtf(var + 1e-5f);
    mu[(size_t)b * D + d0 + t] = m;
  }
  __syncthreads();
  float m = ms[d], r = rss[d];
  #pragma unroll 7
  for (int n = 0; n < 49; ++n) {
    float v = xp[(size_t)n * D];
    zt[d * 224 + q * 49 + n] = f32_to_f8((v - m) * r);
  }
  for (int i = t; i < 64 * 28; i += 256) {
    int dd = i / 28, cc = 196 + i % 28;
    zt[dd * 224 + cc] = 0;
  }
  __syncthreads();
  uint4* dst = (uint4*)(zb + ((size_t)b * D + d0) * 224);
  const uint4* srcl = (const uint4*)zt;
  for (int i = t; i < 896; i += 256) dst[i] = srcl[i];
}

// ---------------------------------------------------------------------------
// Kernel 2a: W1,W2 -> fp8, layout Wf[e][q=mat*7+c][row 0..223][32B].
// grid (7, E, 2); thread = row. Reads line-efficient, writes coalesced.
// ---------------------------------------------------------------------------
__global__ __launch_bounds__(256) void k_convert_f8(
    const float* __restrict__ W1, const float* __restrict__ W2,
    uchar* __restrict__ Wf) {
  int c = blockIdx.x, e = blockIdx.y, mat = blockIdx.z;
  int r = threadIdx.x;
  if (r >= 224) return;
  unsigned int w[8] = {0, 0, 0, 0, 0, 0, 0, 0};
  if (r < 196) {
    const float4* src = (const float4*)((mat ? W2 : W1) +
                         ((size_t)e * 196 + r) * 196 + c * 32);
    int nk4 = (c == 6) ? 1 : 8;
    for (int j = 0; j < nk4; ++j) {
      float4 v = src[j];
      int lo = __builtin_amdgcn_cvt_pk_fp8_f32(v.x, v.y, 0, false);
      w[j] = (unsigned int)__builtin_amdgcn_cvt_pk_fp8_f32(v.z, v.w, lo, true);
    }
  }
  uchar* dst = Wf + (size_t)e * EXB8 + (mat * 7 + c) * CH8 + r * 32;
  uint4 o0 = {w[0], w[1], w[2], w[3]};
  uint4 o1 = {w[4], w[5], w[6], w[7]};
  ((uint4*)dst)[0] = o0;
  ((uint4*)dst)[1] = o1;
}

// Kernel 2b: Wo -> bf16
__global__ void k_convert_wo(const float* __restrict__ Wo, __bf16* __restrict__ Wob) {
  int t = blockIdx.x * 256 + threadIdx.x;
  float4 v = *(const float4*)&Wo[t * 4];
  bf16x4 o = {(__bf16)v.x, (__bf16)v.y, (__bf16)v.z, (__bf16)v.w};
  *(bf16x4*)&Wob[t * 4] = o;
}

// ---------------------------------------------------------------------------
// Kernel 3: router
// ---------------------------------------------------------------------------
__global__ void k_router(const float* __restrict__ mu, const float* __restrict__ Wr,
                         float* __restrict__ probs, int* __restrict__ idxg,
                         float* __restrict__ wg) {
  int b = blockIdx.x;
  int t = threadIdx.x;
  __shared__ float smu[768];
  __shared__ float sp[E];
  __shared__ float smax, ssum;
  __shared__ float svals[TK];
  __shared__ int   sidx[TK];

  for (int i = t; i < 768; i += 256) smu[i] = mu[(size_t)b * D + i];
  __syncthreads();

  float logit = 0.f;
  if (t < E) {
    const float4* wr4 = (const float4*)(Wr + (size_t)t * D);
    const float4* m4  = (const float4*)smu;
    float acc = 0.f;
    #pragma unroll 4
    for (int i = 0; i < 192; ++i) {
      float4 w = wr4[i], m = m4[i];
      acc = fmaf(w.x, m.x, acc); acc = fmaf(w.y, m.y, acc);
      acc = fmaf(w.z, m.z, acc); acc = fmaf(w.w, m.w, acc);
    }
    logit = acc;
    sp[t] = acc;
  }
  __syncthreads();
  if (t == 0) {
    float mx = sp[0];
    for (int e = 1; e < E; ++e) mx = fmaxf(mx, sp[e]);
    smax = mx;
  }
  __syncthreads();
  if (t < E) sp[t] = expf(logit - smax);
  __syncthreads();
  if (t == 0) {
    float s = 0.f;
    for (int e = 0; e < E; ++e) s += sp[e];
    ssum = s;
  }
  __syncthreads();
  if (t < E) {
    sp[t] = sp[t] / ssum;
    probs[(size_t)b * E + t] = sp[t];
  }
  __syncthreads();

  for (int k = 0; k < TK; ++k) {
    if (t < 64) {
      float bv = -1e30f; int bi = 0;
      for (int e = t; e < E; e += 64) {
        float v = sp[e];
        if (v > bv) { bv = v; bi = e; }
      }
      #pragma unroll
      for (int off = 32; off > 0; off >>= 1) {
        float ov = __shfl_down(bv, off);
        int   oi = __shfl_down(bi, off);
        if (ov > bv || (ov == bv && oi < bi)) { bv = ov; bi = oi; }
      }
      if (t == 0) {
        svals[k] = bv; sidx[k] = bi;
        sp[bi] = -2e30f;
      }
    }
    __syncthreads();
  }
  if (t == 0) {
    float s = 0.f;
    for (int k = 0; k < TK; ++k) s += svals[k];
    float inv = 1.0f / s;
    for (int k = 0; k < TK; ++k) {
      wg[b * TK + k]   = svals[k] * inv;
      idxg[b * TK + k] = sidx[k];
    }
  }
}

// ---------------------------------------------------------------------------
// Kernel 4: aux loss -> out[B*N*D]
// ---------------------------------------------------------------------------
__global__ void k_aux(const float* __restrict__ probs, const int* __restrict__ idxg,
                      float* __restrict__ out_aux) {
  __shared__ float cs[E];
  int t = threadIdx.x;
  if (t < E) {
    float s = 0.f;
    for (int b = 0; b < B; ++b) s += probs[(size_t)b * E + t];
    cs[t] = s;
  }
  __syncthreads();
  if (t == 0) {
    float a = 0.f;
    for (int b = 0; b < B; ++b) a += cs[idxg[b * TK]];
    out_aux[0] = a * ((float)E / ((float)B * (float)B));
  }
}

// ---------------------------------------------------------------------------
// Kernel 5: fused expert MLP, fp8 MFMA. 512 thr, 128-row d-tile, 1 block/CU.
// 2-chunk barrier periods (35/block), 4-period prefetch ring (8 chunks in
// flight, contiguous-pair sources). ~119 KB LDS.
// ---------------------------------------------------------------------------
__global__ __launch_bounds__(512, 1) void k_expert(
    const uchar* __restrict__ zb, const uchar* __restrict__ Wf,
    const float* __restrict__ b1, const float* __restrict__ b2,
    const int* __restrict__ idxg, const float* __restrict__ wg,
    __bf16* __restrict__ mixg) {
  __shared__ alignas(16) uchar pool[114688];
  __shared__ __bf16 b1s[5 * 196];
  __shared__ __bf16 b2s[5 * 196];
  __shared__ int   eidx_s[8];
  __shared__ float w_s[8];
  uchar* zs  = pool;                 // 28672: [row 0..127][224 B]
  uchar* at  = pool + 28672;         // 28672: [row 0..127][224 B]
  uchar* wsb = pool + 57344;         // 57344: 4 period buffers x 14336
  __bf16* tb = (__bf16*)(pool + 28672);  // transpose scratch (at+ws region)

  int xw = blockIdx.x & 7, rr_ = blockIdx.x >> 3;
  int j = rr_ / 6, dt = rr_ - j * 6;
  int gid = j * 8 + xw;
  int g = gid & 3, b = gid >> 2;
  int d0 = dt * 128;

  int t = threadIdx.x;
  int lane = t & 63, wave = t >> 6;
  int quad = lane >> 4, l16 = lane & 15;
  int wrow = (wave & 3) * 32;
  int wcol = (wave >> 2) * 112;

  // ---- prologue ----
  if (t < 6) {
    int kc = t < 5 ? t : 4;
    eidx_s[t] = idxg[b * TK + g * 5 + kc];
    if (t < 5) w_s[t] = wg[b * TK + g * 5 + t];
  }
  for (int i = t; i < 980; i += 512) {
    int kk = i / 196, col = i - kk * 196;
    int ee = idxg[b * TK + g * 5 + kk];
    b1s[i] = (__bf16)b1[ee * 196 + col];
    b2s[i] = (__bf16)b2[ee * 196 + col];
  }
  __syncthreads();   // drains prologue vmem (compiler vmcnt0)

  // ---- z staging: flat 28672-B copy, 4 GLDS16/thread ----
  {
    const uchar* zbase = zb + (size_t)(b * D + d0) * 224;
    #pragma unroll
    for (int p = 0; p < 4; ++p) {
      int s = p * 512 + t;
      if (s >= 1792) s -= 1792;    // whole-wave redirect (dup write, same data)
      GLDS16(zbase + s * 16, zs + s * 16);
    }
  }

  // ---- W staging offsets (896 slots/period; waves 6,7 duplicate 0..127) ----
  int soff0 = t * 16;
  int soff1 = (t < 384) ? (512 + t) * 16 : (t - 384) * 16;

  const uchar* wb0 = Wf + (size_t)eidx_s[0] * EXB8;
  #pragma unroll
  for (int pr = 0; pr < 4; ++pr) {   // periods 0..3 = chunk pairs 0,2,4,6
    const uchar* srcp = wb0 + pr * PRB;
    uchar* lb = wsb + pr * PRB;
    GLDS16(srcp + soff0, lb + soff0);
    GLDS16(srcp + soff1, lb + soff1);
  }

  f32x4 macc[14];
  #pragma unroll
  for (int i = 0; i < 14; ++i) macc[i] = (f32x4){0.f, 0.f, 0.f, 0.f};

  #pragma unroll 1
  for (int kk = 0; kk < 5; ++kk) {
    const uchar* wcur = Wf + (size_t)eidx_s[kk] * EXB8;
    const uchar* wnxt = Wf + (size_t)eidx_s[kk + 1] * EXB8;
    float wkv = w_s[kk];

    f32x4 hacc[14];
    #pragma unroll
    for (int i = 0; i < 14; ++i) hacc[i] = (f32x4){0.f, 0.f, 0.f, 0.f};

    auto g1 = [&](const uchar* bp, int c) {
      long a0 = *(const long*)&zs[(wrow + l16) * 224 + c * 32 + quad * 8];
      long a1 = *(const long*)&zs[(wrow + 16 + l16) * 224 + c * 32 + quad * 8];
      #pragma unroll
      for (int ct = 0; ct < 7; ++ct) {
        long bf = *(const long*)&bp[(wcol + ct * 16 + l16) * 32 + quad * 8];
        hacc[ct]     = __builtin_amdgcn_mfma_f32_16x16x32_fp8_fp8(a0, bf, hacc[ct], 0, 0, 0);
        hacc[7 + ct] = __builtin_amdgcn_mfma_f32_16x16x32_fp8_fp8(a1, bf, hacc[7 + ct], 0, 0, 0);
      }
    };
    auto g2 = [&](const uchar* bp, int c) {
      long a0 = *(const long*)&at[(wrow + l16) * 224 + c * 32 + quad * 8];
      long a1 = *(const long*)&at[(wrow + 16 + l16) * 224 + c * 32 + quad * 8];
      #pragma unroll
      for (int ct = 0; ct < 7; ++ct) {
        long bf = *(const long*)&bp[(wcol + ct * 16 + l16) * 32 + quad * 8];
        macc[ct]     = __builtin_amdgcn_mfma_f32_16x16x32_fp8_fp8(a0, bf, macc[ct], 0, 0, 0);
        macc[7 + ct] = __builtin_amdgcn_mfma_f32_16x16x32_fp8_fp8(a1, bf, macc[7 + ct], 0, 0, 0);
      }
    };

    #pragma unroll
    for (int p = 0; p < 7; ++p) {
      uchar* buf = wsb + (((kk * 7 + p) & 3) * PRB);
      WAITVM6;
      BAR;
      if (p < 3) {
        g1(buf, 2 * p); g1(buf + CH8, 2 * p + 1);
      } else if (p == 3) {
        g1(buf, 6);
        // epilogue: a = gelu(h+b1)*w_k -> at (fp8); macc += w_k*b2
        #pragma unroll
        for (int ct = 0; ct < 7; ++ct) {
          int hcol = wcol + ct * 16 + l16;
          bool valid = hcol < 196;
          float bv  = valid ? (float)b1s[kk * 196 + hcol] : 0.f;
          float b2v = valid ? (float)b2s[kk * 196 + hcol] * wkv : 0.f;
          #pragma unroll
          for (int rt = 0; rt < 2; ++rt) {
            f32x4 hv = hacc[rt * 7 + ct];
            #pragma unroll
            for (int rx = 0; rx < 4; ++rx) {
              int row = wrow + rt * 16 + quad * 4 + rx;
              float gv = valid ? gelu_fast(hv[rx] + bv) * wkv : 0.f;
              at[row * 224 + hcol] = f32_to_f8(gv);
              macc[rt * 7 + ct][rx] += b2v;
            }
          }
        }
        WAITLGKM0;
        BAR;
        g2(buf + CH8, 0);
      } else {
        g2(buf, 2 * p - 7); g2(buf + CH8, 2 * p - 6);
      }
      BAR;
      const uchar* isrc = (p < 3) ? (wcur + (8 + 2 * p) * CH8)
                                  : (wnxt + (2 * p - 6) * CH8);
      GLDS16(isrc + soff0, buf + soff0);
      GLDS16(isrc + soff1, buf + soff1);
    }
  }

  // ---- drain async writes, then transpose mix via tb ([n][d], stride 132) ----
  WAITVM0;
  BAR;
  #pragma unroll
  for (int ct = 0; ct < 7; ++ct) {
    int ncol = wcol + ct * 16 + l16;
    #pragma unroll
    for (int rt = 0; rt < 2; ++rt) {
      #pragma unroll
      for (int rx = 0; rx < 4; ++rx) {
        int dr = wrow + rt * 16 + quad * 4 + rx;
        tb[ncol * 132 + dr] = (__bf16)macc[rt * 7 + ct][rx];
      }
    }
  }
  __syncthreads();
  __bf16* mp = mixg + ((size_t)(g * B + b) * N) * D + d0;
  #pragma unroll
  for (int i = 0; i < 7; ++i) {
    int s = i * 512 + t;
    if (s < 3136) {
      int n = s >> 4, c = s & 15;
      const uint2* pa = (const uint2*)&tb[n * 132 + c * 8];
      uint2 v0 = pa[0], v1 = pa[1];
      uint4 v = {v0.x, v0.y, v1.x, v1.y};
      *(uint4*)&mp[(size_t)n * D + c * 8] = v;
    }
  }
}

// ---------------------------------------------------------------------------
// Kernel 6: out = (sum_g mixg_g) @ Wo^T + bo. 64m x 128e tiles, grid 588.
// ---------------------------------------------------------------------------
__global__ __launch_bounds__(256, 2) void k_outproj(
    const __bf16* __restrict__ mixg, const __bf16* __restrict__ Wob,
    const float* __restrict__ bo, float* __restrict__ out) {
  __shared__ alignas(16) __bf16 As[64 * LK];
  __shared__ alignas(16) __bf16 Bs[128 * LK];
  const size_t GS = (size_t)B * N * D;

  int m0 = (blockIdx.x % 98) * 64;
  int e0 = (blockIdx.x / 98) * 128;
  int t = threadIdx.x;
  int lane = t & 63, wave = t >> 6;
  int quad = lane >> 4, l16 = lane & 15;
  int wrow = (wave & 1) * 32;
  int wcol = (wave >> 1) * 64;
  int arow = t >> 2, ach = t & 3;
  const __bf16* ap0 = mixg + (size_t)(m0 + arow) * D + ach * 8;

  f32x4 acc[8];
  #pragma unroll
  for (int i = 0; i < 8; ++i) acc[i] = (f32x4){0.f, 0.f, 0.f, 0.f};

  const uint4* wsrc = (const uint4*)Wob;
  #pragma unroll 1
  for (int c = 0; c < 24; ++c) {
    int k0 = c * 32;
    __syncthreads();
    {
      const __bf16* ap = ap0 + k0;
      bf16x8 g0 = *(const bf16x8*)(ap);
      bf16x8 g1 = *(const bf16x8*)(ap + GS);
      bf16x8 g2 = *(const bf16x8*)(ap + 2 * GS);
      bf16x8 g3 = *(const bf16x8*)(ap + 3 * GS);
      bf16x8 r;
      #pragma unroll
      for (int jj = 0; jj < 8; ++jj)
        r[jj] = (__bf16)((float)g0[jj] + (float)g1[jj] + (float)g2[jj] + (float)g3[jj]);
      *(bf16x8*)&As[arow * LK + ach * 8] = r;
    }
    #pragma unroll
    for (int p = t; p < 512; p += 256) {
      int rr = p >> 2, sub = p & 3;
      uint4 v = wsrc[(((size_t)(e0 + rr)) * D + k0) / 8 + sub];
      *(uint4*)&Bs[rr * LK + sub * 8] = v;
    }
    __syncthreads();
    bf16x8 a0 = *(const bf16x8*)&As[(wrow + l16) * LK + quad * 8];
    bf16x8 a1 = *(const bf16x8*)&As[(wrow + 16 + l16) * LK + quad * 8];
    #pragma unroll
    for (int ct = 0; ct < 4; ++ct) {
      bf16x8 bfr = *(const bf16x8*)&Bs[(wcol + ct * 16 + l16) * LK + quad * 8];
      acc[ct]     = __builtin_amdgcn_mfma_f32_16x16x32_bf16(a0, bfr, acc[ct], 0, 0, 0);
      acc[4 + ct] = __builtin_amdgcn_mfma_f32_16x16x32_bf16(a1, bfr, acc[4 + ct], 0, 0, 0);
    }
  }

  #pragma unroll
  for (int ct = 0; ct < 4; ++ct) {
    int e = e0 + wcol + ct * 16 + l16;
    float bov = bo[e];
    #pragma unroll
    for (int rt = 0; rt < 2; ++rt) {
      #pragma unroll
      for (int rx = 0; rx < 4; ++rx) {
        int m = m0 + wrow + rt * 16 + quad * 4 + rx;
        out[(size_t)m * D + e] = acc[rt * 4 + ct][rx] + bov;
      }
    }
  }
}

// ---------------------------------------------------------------------------
extern "C" void kernel_launch(void* const* d_in, const int* in_sizes, int n_in,
                              void* d_out, int out_size, void* d_ws, size_t ws_size,
                              hipStream_t stream) {
  const float* x  = (const float*)d_in[0];
  const float* Wr = (const float*)d_in[1];
  const float* W1 = (const float*)d_in[2];
  const float* b1 = (const float*)d_in[3];
  const float* W2 = (const float*)d_in[4];
  const float* b2 = (const float*)d_in[5];
  const float* Wo = (const float*)d_in[6];
  const float* bo = (const float*)d_in[7];
  float* out = (float*)d_out;

  char* p = (char*)d_ws;
  auto alloc = [&](size_t bytes) {
    char* r = p;
    p += (bytes + 255) & ~(size_t)255;
    return r;
  };
  uchar*  zb   = (uchar*)alloc((size_t)B * D * 224);
  float*  mu   = (float*)alloc((size_t)B * D * 4);
  uchar*  Wf   = (uchar*)alloc((size_t)E * EXB8);
  __bf16* Wob  = (__bf16*)alloc((size_t)D * D * 2);
  __bf16* mixg = (__bf16*)alloc((size_t)NGRP * B * N * D * 2);
  float*  probs= (float*)alloc((size_t)B * E * 4);
  int*    idxg = (int*)alloc((size_t)B * TK * 4);
  float*  wg   = (float*)alloc((size_t)B * TK * 4);

  k_ln<<<dim3(B * 12), dim3(256), 0, stream>>>(x, zb, mu);
  k_convert_f8<<<dim3(7, E, 2), dim3(256), 0, stream>>>(W1, W2, Wf);
  k_convert_wo<<<dim3(576), dim3(256), 0, stream>>>(Wo, Wob);
  k_router<<<dim3(B), dim3(256), 0, stream>>>(mu, Wr, probs, idxg, wg);
  k_aux<<<dim3(1), dim3(256), 0, stream>>>(probs, idxg, out + (size_t)B * N * D);
  k_expert<<<dim3(768), dim3(512), 0, stream>>>(zb, Wf, b1, b2, idxg, wg, mixg);
  k_outproj<<<dim3(588), dim3(256), 0, stream>>>(mixg, Wob, bo, out);
}

// Round 6
// 419.117 us; speedup vs baseline: 1.1343x; 1.1343x over previous
//
#include <hip/hip_runtime.h>
#include <math.h>

// ---- problem constants ----
constexpr int B  = 32;
constexpr int N  = 196;
constexpr int D  = 768;
constexpr int E  = 200;
constexpr int TK = 20;

constexpr int NGRP = 4;        // expert groups (5 experts each)
constexpr int PRB  = 14336;    // period buffer bytes: 224 cols x 64 B (64 k fp8)
constexpr int EXB  = 114688;   // per expert: 2 matrices x 4 periods x PRB
constexpr int LK   = 40;       // k_outproj LDS stride

typedef __bf16 bf16x8 __attribute__((ext_vector_type(8)));
typedef __bf16 bf16x4 __attribute__((ext_vector_type(4)));
typedef float  f32x4  __attribute__((ext_vector_type(4)));
typedef long   longx2 __attribute__((ext_vector_type(2)));
typedef unsigned char uchar;

#define GLDS16(gp, lp)                                                        \
  __builtin_amdgcn_global_load_lds(                                           \
      (const __attribute__((address_space(1))) void*)(gp),                    \
      (__attribute__((address_space(3))) void*)(lp), 16, 0, 0)

// s_waitcnt immediates (gfx9: vm[3:0] | exp[6:4] | lgkm[11:8] | vm[5:4]@[15:14])
#define WAITVM8   __builtin_amdgcn_s_waitcnt(0x0F78)
#define WAITVM6   __builtin_amdgcn_s_waitcnt(0x0F76)
#define WAITVM0   __builtin_amdgcn_s_waitcnt(0x0F70)
#define WAITLGKM0 __builtin_amdgcn_s_waitcnt(0xC07F)
#define BAR       __builtin_amdgcn_s_barrier()

__device__ __forceinline__ float gelu_fast(float x) {
  float u = x * fmaf(x * x, 0.044715f, 1.0f);
  float e = exp2f(-2.3022084f * u);
  return x * __builtin_amdgcn_rcpf(1.0f + e);
}

__device__ __forceinline__ uchar f32_to_f8(float v) {
  return (uchar)(__builtin_amdgcn_cvt_pk_fp8_f32(v, v, 0, false) & 0xff);
}

// ---------------------------------------------------------------------------
// Kernel 1: token-mean + LN over N -> z fp8 in expert-staging layout:
// zb[b][pair 0..3][d 0..767][64B], 64B = [q_phys][even-chunk 8B|odd-chunk 8B],
// q_phys = ((tok>>3)&3) ^ (d&3).  Tokens 196..255 zero.
// ---------------------------------------------------------------------------
__global__ __launch_bounds__(256) void k_ln(const float* __restrict__ x,
                                            uchar* __restrict__ zb,
                                            float* __restrict__ mu) {
  int b = blockIdx.x / 12, dt = blockIdx.x % 12;
  int d0 = dt * 64;
  int t = threadIdx.x;
  int q = t >> 6, d = t & 63;
  __shared__ float ps[256], pq[256];
  __shared__ float ms[64], rss[64];
  __shared__ alignas(16) uchar zt[64 * 256];

  for (int i = t; i < 1024; i += 256) ((uint4*)zt)[i] = (uint4){0, 0, 0, 0};

  const float* xp = x + ((size_t)b * N + q * 49) * D + d0 + d;
  float s = 0.f, sq = 0.f;
  #pragma unroll 7
  for (int n = 0; n < 49; ++n) {
    float v = xp[(size_t)n * D];
    s += v; sq += v * v;
  }
  ps[t] = s; pq[t] = sq;
  __syncthreads();
  if (t < 64) {
    float S = ps[t] + ps[t + 64] + ps[t + 128] + ps[t + 192];
    float Q = pq[t] + pq[t + 64] + pq[t + 128] + pq[t + 192];
    float m = S * (1.0f / N);
    float var = Q * (1.0f / N) - m * m;
    ms[t] = m; rss[t] = rsqrtf(var + 1e-5f);
    mu[(size_t)b * D + d0 + t] = m;
  }
  __syncthreads();
  float m = ms[d], r = rss[d];
  int dsw = d & 3;
  #pragma unroll 7
  for (int n = 0; n < 49; ++n) {
    float v = xp[(size_t)n * D];
    int tok = q * 49 + n;
    int qp = ((tok >> 3) & 3) ^ dsw;
    int off = d * 256 + (tok >> 6) * 64 + qp * 16 + ((tok >> 5) & 1) * 8 + (tok & 7);
    zt[off] = f32_to_f8((v - m) * r);
  }
  __syncthreads();
  #pragma unroll
  for (int pair = 0; pair < 4; ++pair) {
    uint4* dst = (uint4*)(zb + (((size_t)b * 4 + pair) * 768 + d0) * 64);
    dst[t] = ((const uint4*)zt)[(t >> 2) * 16 + pair * 4 + (t & 3)];
  }
}

// ---------------------------------------------------------------------------
// Kernel 2: W1,W2 -> fp8 period format Wf[e][mat*4+p][col][q_phys][16B]
// via LDS; plus Wo -> bf16 (blocks >= 400).
// ---------------------------------------------------------------------------
__global__ __launch_bounds__(256) void k_convert(
    const float* __restrict__ W1, const float* __restrict__ W2,
    const float* __restrict__ Wo,
    uchar* __restrict__ Wf, __bf16* __restrict__ Wob) {
  int bx = blockIdx.x;
  int t = threadIdx.x;
  if (bx >= 400) {
    int i = (bx - 400) * 256 + t;
    float4 v = *(const float4*)&Wo[(size_t)i * 4];
    bf16x4 o = {(__bf16)v.x, (__bf16)v.y, (__bf16)v.z, (__bf16)v.w};
    *(bf16x4*)&Wob[(size_t)i * 4] = o;
    return;
  }
  int e = bx >> 1, mat = bx & 1;
  __shared__ alignas(16) uchar ls[224 * 256];   // [row][k], zero-padded
  for (int i = t; i < 3584; i += 256) ((uint4*)ls)[i] = (uint4){0, 0, 0, 0};
  __syncthreads();
  const float* src = (mat ? W2 : W1) + (size_t)e * 196 * 196;
  for (int i = t; i < 196 * 49; i += 256) {
    int r = i / 49, c4 = (i - r * 49) * 4;
    float4 v = *(const float4*)&src[(size_t)r * 196 + c4];
    int lo = __builtin_amdgcn_cvt_pk_fp8_f32(v.x, v.y, 0, false);
    unsigned int pk = (unsigned int)__builtin_amdgcn_cvt_pk_fp8_f32(v.z, v.w, lo, true);
    *(unsigned int*)&ls[r * 256 + c4] = pk;
  }
  __syncthreads();
  uchar* dst = Wf + (size_t)e * EXB + mat * 4 * PRB;
  for (int s = t; s < 3584; s += 256) {
    int p = s / 896, rem = s - p * 896;
    int col = rem >> 2, qp = rem & 3;
    int ql = qp ^ (col & 3);
    unsigned long lo = *(const unsigned long*)&ls[col * 256 + p * 64 + ql * 8];
    unsigned long hi = *(const unsigned long*)&ls[col * 256 + p * 64 + 32 + ql * 8];
    longx2 o; o[0] = (long)lo; o[1] = (long)hi;
    *(longx2*)&dst[(size_t)s * 16] = o;
  }
}

// ---------------------------------------------------------------------------
// Kernel 3: router
// ---------------------------------------------------------------------------
__global__ void k_router(const float* __restrict__ mu, const float* __restrict__ Wr,
                         float* __restrict__ probs, int* __restrict__ idxg,
                         float* __restrict__ wg) {
  int b = blockIdx.x;
  int t = threadIdx.x;
  __shared__ float smu[768];
  __shared__ float sp[E];
  __shared__ float smax, ssum;
  __shared__ float svals[TK];
  __shared__ int   sidx[TK];

  for (int i = t; i < 768; i += 256) smu[i] = mu[(size_t)b * D + i];
  __syncthreads();

  float logit = 0.f;
  if (t < E) {
    const float4* wr4 = (const float4*)(Wr + (size_t)t * D);
    const float4* m4  = (const float4*)smu;
    float acc = 0.f;
    #pragma unroll 4
    for (int i = 0; i < 192; ++i) {
      float4 w = wr4[i], m = m4[i];
      acc = fmaf(w.x, m.x, acc); acc = fmaf(w.y, m.y, acc);
      acc = fmaf(w.z, m.z, acc); acc = fmaf(w.w, m.w, acc);
    }
    logit = acc;
    sp[t] = acc;
  }
  __syncthreads();
  if (t == 0) {
    float mx = sp[0];
    for (int e = 1; e < E; ++e) mx = fmaxf(mx, sp[e]);
    smax = mx;
  }
  __syncthreads();
  if (t < E) sp[t] = expf(logit - smax);
  __syncthreads();
  if (t == 0) {
    float s = 0.f;
    for (int e = 0; e < E; ++e) s += sp[e];
    ssum = s;
  }
  __syncthreads();
  if (t < E) {
    sp[t] = sp[t] / ssum;
    probs[(size_t)b * E + t] = sp[t];
  }
  __syncthreads();

  for (int k = 0; k < TK; ++k) {
    if (t < 64) {
      float bv = -1e30f; int bi = 0;
      for (int e = t; e < E; e += 64) {
        float v = sp[e];
        if (v > bv) { bv = v; bi = e; }
      }
      #pragma unroll
      for (int off = 32; off > 0; off >>= 1) {
        float ov = __shfl_down(bv, off);
        int   oi = __shfl_down(bi, off);
        if (ov > bv || (ov == bv && oi < bi)) { bv = ov; bi = oi; }
      }
      if (t == 0) {
        svals[k] = bv; sidx[k] = bi;
        sp[bi] = -2e30f;
      }
    }
    __syncthreads();
  }
  if (t == 0) {
    float s = 0.f;
    for (int k = 0; k < TK; ++k) s += svals[k];
    float inv = 1.0f / s;
    for (int k = 0; k < TK; ++k) {
      wg[b * TK + k]   = svals[k] * inv;
      idxg[b * TK + k] = sidx[k];
    }
  }
}

// ---------------------------------------------------------------------------
// Kernel 5: fused expert MLP, fp8 MFMA, conflict-free pair layout.
// 512 thr, 128-row d-tile, 1 block/CU, 4-period prefetch ring.
// ---------------------------------------------------------------------------
__global__ __launch_bounds__(512, 1) void k_expert(
    const uchar* __restrict__ zb, const uchar* __restrict__ Wf,
    const float* __restrict__ b1, const float* __restrict__ b2,
    const int* __restrict__ idxg, const float* __restrict__ wg,
    __bf16* __restrict__ mixg) {
  __shared__ alignas(16) uchar pool[122880];
  __shared__ __bf16 b1s[5 * 196];
  __shared__ __bf16 b2s[5 * 196];
  __shared__ int   eidx_s[5];
  __shared__ float w_s[5];
  uchar* zs  = pool;                 // 32768: [pair][row 0..127][64B]
  uchar* at  = pool + 32768;         // 32768: same layout (k = h)
  uchar* wsb = pool + 65536;         // 57344: 4 ring buffers x 14336
  __bf16* tb = (__bf16*)(pool + 32768);  // epilogue transpose scratch

  int xw = blockIdx.x & 7, rr_ = blockIdx.x >> 3;
  int j = rr_ / 6, dt = rr_ - j * 6;
  int gid = j * 8 + xw;
  int g = gid & 3, b = gid >> 2;
  int d0 = dt * 128;

  int t = threadIdx.x;
  int lane = t & 63, wave = t >> 6;
  int quad = lane >> 4, l16 = lane & 15;
  int wrow = (wave & 3) * 32;
  int wcol = (wave >> 2) * 112;
  int qp = quad ^ (l16 & 3);         // shared XOR-swizzle for A and B frags

  // ---- prologue ----
  if (t < 5) {
    eidx_s[t] = idxg[b * TK + g * 5 + t];
    w_s[t]    = wg[b * TK + g * 5 + t];
  }
  for (int i = t; i < 980; i += 512) {
    int kk = i / 196, col = i - kk * 196;
    int ee = idxg[b * TK + g * 5 + kk];
    b1s[i] = (__bf16)b1[ee * 196 + col];
    b2s[i] = (__bf16)b2[ee * 196 + col];
  }
  // one-time zero of at's k-pad (chunk 7 = hi 8B of each 16B in pair 3)
  *(unsigned long*)&at[3 * 8192 + (t >> 2) * 64 + (t & 3) * 16 + 8] = 0ul;
  __syncthreads();   // drains prologue vmem

  // ---- z staging: 4 flat 8192-B pair blocks ----
  {
    const uchar* zbase = zb + ((size_t)b * 4 * 768 + d0) * 64;
    #pragma unroll
    for (int p = 0; p < 4; ++p)
      GLDS16(zbase + (size_t)p * (768 * 64) + t * 16, zs + p * 8192 + t * 16);
  }

  // ---- W ring staging offsets (896 slots; waves 6,7 duplicate 0..127) ----
  int soff0 = t * 16;
  int soff1 = (t < 384) ? (512 + t) * 16 : (t - 384) * 16;

  auto issue = [&](int qn) {
    int qq = qn > 39 ? 39 : qn;
    int kk2 = qq >> 3, rem = qq & 7;
    const uchar* src = Wf + (size_t)eidx_s[kk2] * EXB + rem * PRB;
    uchar* lb = wsb + (qn & 3) * PRB;
    GLDS16(src + soff0, lb + soff0);
    GLDS16(src + soff1, lb + soff1);
  };
  issue(0); issue(1); issue(2); issue(3);

  // ---- hoist z A-frags (shared across all 5 experts) ----
  WAITVM8;   // z staging (oldest 4 vmem) done; ring still in flight
  BAR;
  longx2 zf[4][2];
  #pragma unroll
  for (int p = 0; p < 4; ++p) {
    zf[p][0] = *(const longx2*)&zs[p * 8192 + (wrow + l16) * 64 + qp * 16];
    zf[p][1] = *(const longx2*)&zs[p * 8192 + (wrow + 16 + l16) * 64 + qp * 16];
  }

  f32x4 macc[14];
  #pragma unroll
  for (int i = 0; i < 14; ++i) macc[i] = (f32x4){0.f, 0.f, 0.f, 0.f};

  #pragma unroll 1
  for (int kk = 0; kk < 5; ++kk) {
    float wkv = w_s[kk];
    f32x4 hacc[14];
    #pragma unroll
    for (int i = 0; i < 14; ++i) hacc[i] = (f32x4){0.f, 0.f, 0.f, 0.f};

    // ---- GEMM1: 4 periods ----
    #pragma unroll 1
    for (int p = 0; p < 4; ++p) {
      int q = kk * 8 + p;
      WAITVM6;
      BAR;
      const uchar* buf = wsb + (q & 3) * PRB;
      #pragma unroll
      for (int ct = 0; ct < 7; ++ct) {
        longx2 bf = *(const longx2*)&buf[(wcol + ct * 16 + l16) * 64 + qp * 16];
        hacc[ct]     = __builtin_amdgcn_mfma_f32_16x16x32_fp8_fp8(zf[p][0][0], bf[0], hacc[ct], 0, 0, 0);
        hacc[ct]     = __builtin_amdgcn_mfma_f32_16x16x32_fp8_fp8(zf[p][0][1], bf[1], hacc[ct], 0, 0, 0);
        hacc[7 + ct] = __builtin_amdgcn_mfma_f32_16x16x32_fp8_fp8(zf[p][1][0], bf[0], hacc[7 + ct], 0, 0, 0);
        hacc[7 + ct] = __builtin_amdgcn_mfma_f32_16x16x32_fp8_fp8(zf[p][1][1], bf[1], hacc[7 + ct], 0, 0, 0);
      }
      BAR;
      issue(q + 4);
    }

    // ---- epilogue: a = gelu(h+b1)*w_k -> at (swizzled fp8); macc += w_k*b2 ----
    #pragma unroll
    for (int ct = 0; ct < 7; ++ct) {
      int hcol = wcol + ct * 16 + l16;
      bool valid = hcol < 196;
      float bv  = valid ? (float)b1s[kk * 196 + hcol] : 0.f;
      float b2v = valid ? (float)b2s[kk * 196 + hcol] * wkv : 0.f;
      int hbase = (hcol >> 6) * 8192 + ((hcol >> 5) & 1) * 8 + (hcol & 7);
      int hq = (hcol >> 3) & 3;
      #pragma unroll
      for (int rt = 0; rt < 2; ++rt) {
        f32x4 hv = hacc[rt * 7 + ct];
        #pragma unroll
        for (int rx = 0; rx < 4; ++rx) {
          int row = wrow + rt * 16 + quad * 4 + rx;
          float gv = valid ? gelu_fast(hv[rx] + bv) * wkv : 0.f;
          at[hbase + row * 64 + (hq ^ rx) * 16] = f32_to_f8(gv);
          macc[rt * 7 + ct][rx] += b2v;
        }
      }
    }
    WAITLGKM0;   // own at-writes drained before the next barrier

    // ---- GEMM2: 4 periods ----
    #pragma unroll 1
    for (int p = 0; p < 4; ++p) {
      int q = kk * 8 + 4 + p;
      WAITVM6;
      BAR;
      const uchar* buf = wsb + (q & 3) * PRB;
      longx2 a0 = *(const longx2*)&at[p * 8192 + (wrow + l16) * 64 + qp * 16];
      longx2 a1 = *(const longx2*)&at[p * 8192 + (wrow + 16 + l16) * 64 + qp * 16];
      #pragma unroll
      for (int ct = 0; ct < 7; ++ct) {
        longx2 bf = *(const longx2*)&buf[(wcol + ct * 16 + l16) * 64 + qp * 16];
        macc[ct]     = __builtin_amdgcn_mfma_f32_16x16x32_fp8_fp8(a0[0], bf[0], macc[ct], 0, 0, 0);
        macc[ct]     = __builtin_amdgcn_mfma_f32_16x16x32_fp8_fp8(a0[1], bf[1], macc[ct], 0, 0, 0);
        macc[7 + ct] = __builtin_amdgcn_mfma_f32_16x16x32_fp8_fp8(a1[0], bf[0], macc[7 + ct], 0, 0, 0);
        macc[7 + ct] = __builtin_amdgcn_mfma_f32_16x16x32_fp8_fp8(a1[1], bf[1], macc[7 + ct], 0, 0, 0);
      }
      BAR;
      issue(q + 4);
    }
  }

  // ---- drain async, transpose mix via tb ([n][d], stride 132), write ----
  WAITVM0;
  BAR;
  #pragma unroll
  for (int ct = 0; ct < 7; ++ct) {
    int ncol = wcol + ct * 16 + l16;
    #pragma unroll
    for (int rt = 0; rt < 2; ++rt) {
      #pragma unroll
      for (int rx = 0; rx < 4; ++rx) {
        int dr = wrow + rt * 16 + quad * 4 + rx;
        tb[ncol * 132 + dr] = (__bf16)macc[rt * 7 + ct][rx];
      }
    }
  }
  __syncthreads();
  __bf16* mp = mixg + ((size_t)(g * B + b) * N) * D + d0;
  #pragma unroll
  for (int i = 0; i < 7; ++i) {
    int s = i * 512 + t;
    if (s < 3136) {
      int n = s >> 4, c = s & 15;
      const uint2* pa = (const uint2*)&tb[n * 132 + c * 8];
      uint2 v0 = pa[0], v1 = pa[1];
      uint4 v = {v0.x, v0.y, v1.x, v1.y};
      *(uint4*)&mp[(size_t)n * D + c * 8] = v;
    }
  }
}

// ---------------------------------------------------------------------------
// Kernel 6: out = (sum_g mixg_g) @ Wo^T + bo; block 0 also computes aux loss.
// ---------------------------------------------------------------------------
__global__ __launch_bounds__(256, 2) void k_outproj(
    const __bf16* __restrict__ mixg, const __bf16* __restrict__ Wob,
    const float* __restrict__ bo, const float* __restrict__ probs,
    const int* __restrict__ idxg, float* __restrict__ out,
    float* __restrict__ out_aux) {
  __shared__ alignas(16) __bf16 As[64 * LK];
  __shared__ alignas(16) __bf16 Bs[256 * LK];
  const size_t GS = (size_t)B * N * D;

  int t = threadIdx.x;
  if (blockIdx.x == 0 && t < 32) {
    int top1 = idxg[t * TK];
    float s = 0.f;
    for (int bb = 0; bb < B; ++bb) s += probs[(size_t)bb * E + top1];
    #pragma unroll
    for (int off = 16; off > 0; off >>= 1) s += __shfl_down(s, off);
    if (t == 0) out_aux[0] = s * ((float)E / ((float)B * (float)B));
  }

  int m0 = (blockIdx.x % 98) * 64;
  int e0 = (blockIdx.x / 98) * 256;
  int lane = t & 63, wave = t >> 6;
  int quad = lane >> 4, l16 = lane & 15;
  int wrow = (wave & 1) * 32;
  int wcol = (wave >> 1) * 128;
  int arow = t >> 2, ach = t & 3;
  const __bf16* ap0 = mixg + (size_t)(m0 + arow) * D + ach * 8;

  f32x4 acc[16];
  #pragma unroll
  for (int i = 0; i < 16; ++i) acc[i] = (f32x4){0.f, 0.f, 0.f, 0.f};

  const uint4* wsrc = (const uint4*)Wob;
  #pragma unroll 1
  for (int c = 0; c < 24; ++c) {
    int k0 = c * 32;
    __syncthreads();
    {
      const __bf16* ap = ap0 + k0;
      bf16x8 g0 = *(const bf16x8*)(ap);
      bf16x8 g1 = *(const bf16x8*)(ap + GS);
      bf16x8 g2 = *(const bf16x8*)(ap + 2 * GS);
      bf16x8 g3 = *(const bf16x8*)(ap + 3 * GS);
      bf16x8 r;
      #pragma unroll
      for (int jj = 0; jj < 8; ++jj)
        r[jj] = (__bf16)((float)g0[jj] + (float)g1[jj] + (float)g2[jj] + (float)g3[jj]);
      *(bf16x8*)&As[arow * LK + ach * 8] = r;
    }
    for (int p = t; p < 1024; p += 256) {
      int rr = p >> 2, sub = p & 3;
      uint4 v = wsrc[(((size_t)(e0 + rr)) * D + k0) / 8 + sub];
      *(uint4*)&Bs[rr * LK + sub * 8] = v;
    }
    __syncthreads();
    bf16x8 a0 = *(const bf16x8*)&As[(wrow + l16) * LK + quad * 8];
    bf16x8 a1 = *(const bf16x8*)&As[(wrow + 16 + l16) * LK + quad * 8];
    #pragma unroll
    for (int ct = 0; ct < 8; ++ct) {
      bf16x8 bfr = *(const bf16x8*)&Bs[(wcol + ct * 16 + l16) * LK + quad * 8];
      acc[ct]     = __builtin_amdgcn_mfma_f32_16x16x32_bf16(a0, bfr, acc[ct], 0, 0, 0);
      acc[8 + ct] = __builtin_amdgcn_mfma_f32_16x16x32_bf16(a1, bfr, acc[8 + ct], 0, 0, 0);
    }
  }

  #pragma unroll
  for (int ct = 0; ct < 8; ++ct) {
    int e = e0 + wcol + ct * 16 + l16;
    float bov = bo[e];
    #pragma unroll
    for (int rt = 0; rt < 2; ++rt) {
      #pragma unroll
      for (int rx = 0; rx < 4; ++rx) {
        int m = m0 + wrow + rt * 16 + quad * 4 + rx;
        out[(size_t)m * D + e] = acc[rt * 8 + ct][rx] + bov;
      }
    }
  }
}

// ---------------------------------------------------------------------------
extern "C" void kernel_launch(void* const* d_in, const int* in_sizes, int n_in,
                              void* d_out, int out_size, void* d_ws, size_t ws_size,
                              hipStream_t stream) {
  const float* x  = (const float*)d_in[0];
  const float* Wr = (const float*)d_in[1];
  const float* W1 = (const float*)d_in[2];
  const float* b1 = (const float*)d_in[3];
  const float* W2 = (const float*)d_in[4];
  const float* b2 = (const float*)d_in[5];
  const float* Wo = (const float*)d_in[6];
  const float* bo = (const float*)d_in[7];
  float* out = (float*)d_out;

  char* p = (char*)d_ws;
  auto alloc = [&](size_t bytes) {
    char* r = p;
    p += (bytes + 255) & ~(size_t)255;
    return r;
  };
  uchar*  zb   = (uchar*)alloc((size_t)B * 4 * 768 * 64);
  float*  mu   = (float*)alloc((size_t)B * D * 4);
  uchar*  Wf   = (uchar*)alloc((size_t)E * EXB);
  __bf16* Wob  = (__bf16*)alloc((size_t)D * D * 2);
  __bf16* mixg = (__bf16*)alloc((size_t)NGRP * B * N * D * 2);
  float*  probs= (float*)alloc((size_t)B * E * 4);
  int*    idxg = (int*)alloc((size_t)B * TK * 4);
  float*  wg   = (float*)alloc((size_t)B * TK * 4);

  k_ln<<<dim3(B * 12), dim3(256), 0, stream>>>(x, zb, mu);
  k_convert<<<dim3(976), dim3(256), 0, stream>>>(W1, W2, Wo, Wf, Wob);
  k_router<<<dim3(B), dim3(256), 0, stream>>>(mu, Wr, probs, idxg, wg);
  k_expert<<<dim3(768), dim3(512), 0, stream>>>(zb, Wf, b1, b2, idxg, wg, mixg);
  k_outproj<<<dim3(294), dim3(256), 0, stream>>>(mixg, Wob, bo, probs, idxg,
                                                 out, out + (size_t)B * N * D);
}